// Round 2
// baseline (587.690 us; speedup 1.0000x reference)
//
#include <hip/hip_runtime.h>

// PhonologicalLoopMemory: out[b] = concat(recent[0..3], rehearsal), each slice 128*256 fp32.
//   recent[0] = features[b]                     (buf[pos] overwritten with features before read)
//   recent[j] = 0.9 * feature_buffer[b, (pos-j) & 63]   for j=1..3, if j < num_valid else 0
//   rehearsal = features[b]
//   num_valid = buffer_filled[b] ? 64 : pos+1
// Pure memory movement, every byte touched exactly once:
//   - explicit load phase (4 independent global loads -> max MLP per thread)
//   - nontemporal loads/stores (streaming data, avoid L2/L3 pollution)
//     NOTE: must use clang ext_vector type, not HIP float4 (builtin rejects class types)
//   - b is block-uniform (32 blocks/batch @ 256 thr) -> pos/filled scalar, branches wave-uniform

typedef float f32x4 __attribute__((ext_vector_type(4)));

constexpr int FEATURE_DIM = 128;
constexpr int WINDOW_LEN  = 256;
constexpr int BUFFER_LEN  = 64;
constexpr int NUM_RECENT  = 4;
constexpr int BATCH       = 64;
constexpr int FW   = FEATURE_DIM * WINDOW_LEN;   // 32768 floats per slice
constexpr int FW4  = FW / 4;                     // 8192 float4 per slice
constexpr int THREADS_TOTAL = BATCH * FW4;       // 524288

__global__ __launch_bounds__(256) void plm_kernel(
    const f32x4* __restrict__ features,       // [B, FW4]
    const f32x4* __restrict__ feature_buffer, // [B, 64, FW4]
    const int*   __restrict__ current_pos,    // [B]
    const int*   __restrict__ buffer_filled,  // [B] (bool as int32)
    f32x4*       __restrict__ out)            // [B, 5, FW4]
{
    int i = blockIdx.x * blockDim.x + threadIdx.x;   // 0 .. 524287
    int b = i >> 13;            // / FW4  (block-uniform)
    int k = i & (FW4 - 1);      // coalesced inner index

    int pos       = current_pos[b];
    int filled    = buffer_filled[b];
    int num_valid = filled ? BUFFER_LEN : (pos + 1);

    const f32x4* bb = feature_buffer + (size_t)b * BUFFER_LEN * FW4;

    // ---- load phase: all independent, issued back-to-back ----
    f32x4 f = __builtin_nontemporal_load(&features[(size_t)b * FW4 + k]);

    f32x4 r[NUM_RECENT - 1];
#pragma unroll
    for (int j = 1; j < NUM_RECENT; ++j) {
        f32x4 v = (f32x4){0.0f, 0.0f, 0.0f, 0.0f};
        if (j < num_valid) {                          // wave-uniform branch
            int p = (pos - j) & (BUFFER_LEN - 1);     // mod 64
            f32x4 s = __builtin_nontemporal_load(&bb[(size_t)p * FW4 + k]);
            v = 0.9f * s;
        }
        r[j - 1] = v;
    }

    // ---- store phase ----
    f32x4* ob = out + (size_t)b * (NUM_RECENT + 1) * FW4;
    __builtin_nontemporal_store(f, &ob[k]);                      // recent[0]
#pragma unroll
    for (int j = 1; j < NUM_RECENT; ++j)
        __builtin_nontemporal_store(r[j - 1], &ob[j * FW4 + k]); // recent[1..3]
    __builtin_nontemporal_store(f, &ob[4 * FW4 + k]);            // rehearsal
}

extern "C" void kernel_launch(void* const* d_in, const int* in_sizes, int n_in,
                              void* d_out, int out_size, void* d_ws, size_t ws_size,
                              hipStream_t stream) {
    const f32x4* features       = (const f32x4*)d_in[0];
    const f32x4* feature_buffer = (const f32x4*)d_in[1];
    const int*   current_pos    = (const int*)d_in[2];
    const int*   buffer_filled  = (const int*)d_in[3];
    f32x4*       out            = (f32x4*)d_out;

    int blocks = THREADS_TOTAL / 256;   // 2048 blocks
    plm_kernel<<<blocks, 256, 0, stream>>>(features, feature_buffer,
                                           current_pos, buffer_filled, out);
}